// Round 6
// baseline (897.488 us; speedup 1.0000x reference)
//
#include <hip/hip_runtime.h>
#include <hip/hip_bf16.h>
#include <stdint.h>

typedef __attribute__((ext_vector_type(8))) short short8;
typedef __attribute__((ext_vector_type(4))) float f32x4;
typedef unsigned long long u64;

#define DI static __device__ __forceinline__

DI unsigned short f2b(float f){
  unsigned u = __float_as_uint(f);
  u = (u + 0x7FFFu + ((u >> 16) & 1u)) >> 16;
  return (unsigned short)u;
}
DI float sigm(float x){ return 1.0f / (1.0f + __expf(-x)); }
DI float tanh_(float x){ return 1.0f - 2.0f / (__expf(2.0f*x) + 1.0f); } // safe at +/-inf
DI unsigned pk2(unsigned short a, unsigned short b){ return (unsigned)a | ((unsigned)b << 16); }

// ---- embedding gather: Xbf[r' = t*64+b][256] = bf16(emb[input[b][t]])
__global__ void k_gather(const int* __restrict__ inp, const float* __restrict__ emb,
                         unsigned short* __restrict__ Xbf){
  int r = blockIdx.x;            // r' = t*64 + b
  int t = r >> 6, b = r & 63;
  int idx = inp[b*128 + t];
  float v = emb[(size_t)idx*256 + threadIdx.x];
  Xbf[(size_t)r*256 + threadIdx.x] = f2b(v);
}

// ---- transpose src[R][C] (rows row0..row0+R-1, ld) -> dst[n(C)][R]
// BF: bf16 output. REORD: gate-interleave columns n' = (c&255)*4 + (c>>8)
template<int BF, int REORD>
__global__ void k_transpose(const float* __restrict__ src, void* __restrict__ dst,
                            int R, int C, int ld, int row0){
  __shared__ float tile[32][33];
  int tx = threadIdx.x, ty = threadIdx.y;
  int x = blockIdx.x*32 + tx;
  for (int i = 0; i < 4; i++){
    int y = blockIdx.y*32 + ty + i*8;
    if (x < C && y < R) tile[ty + i*8][tx] = src[(size_t)(row0 + y)*ld + x];
  }
  __syncthreads();
  int y2 = blockIdx.y*32 + tx;                 // R index
  for (int i = 0; i < 4; i++){
    int x2 = blockIdx.x*32 + ty + i*8;         // C index
    if (x2 < C && y2 < R){
      float v = tile[tx][ty + i*8];
      int n = REORD ? ((x2 & 255)*4 + (x2 >> 8)) : x2;
      if (BF) ((unsigned short*)dst)[(size_t)n*R + y2] = f2b(v);
      else    ((float*)dst)[(size_t)n*R + y2] = v;
    }
  }
}

// ---- MFMA GEMM, 2-phase double-buffered staging (T3 minimum pipeline):
// STAGE(t+1) issued BEFORE compute(t); counted s_waitcnt vmcnt(8) + raw s_barrier
// (no compiler vmcnt(0) drain) keeps the prefetch in flight across the barrier;
// second raw barrier after compute protects buffer reuse. K=256 -> 4 K-steps.
// C[m][n] = sum_k A[m][k]*Bt[n][k], A/Bt bf16 [rows][256].
// Block mapping: m0 = blockIdx.x (fast) so consecutive blocks share the same B-tile.
// EPI 0: Z0x store (+bias b0 with gate-reorder un-map), rows r'=(t,b) -> Z0x[t][n'][b]
// EPI 1: fused softmax partial: S[row] += sum exp(logit+bias); LT[row] = logit_tgt
template<int EPI>
__launch_bounds__(256, 2)
__global__ void k_gemm(const unsigned short* __restrict__ A, const unsigned short* __restrict__ Bt,
                       float* __restrict__ outZ, const float* __restrict__ bias,
                       const int* __restrict__ tgt, float* __restrict__ S, float* __restrict__ LT){
  __shared__ unsigned short As[2][128*64];
  __shared__ unsigned short Bs[2][128*64];
  __shared__ int tgt_s[128];
  const int m0 = blockIdx.x*128, n0 = blockIdx.y*128;
  const int tid = threadIdx.x;
  const int w = tid >> 6, l = tid & 63;
  const int quad = l >> 4, l15 = l & 15;
  const int wm = (w >> 1)*64, wn = (w & 1)*64;
  const int lrow = l >> 3, ls = l & 7;         // lane -> (row-in-group, slot)
  f32x4 acc[4][4] = {};
  if (EPI == 1 && tid < 128) tgt_s[tid] = tgt[m0 + tid];

  // stage K-step (k0 = step*64) into buffer buf: 8 global_load_lds per thread-row-group
  auto STAGE = [&](int buf, int k0){
    #pragma unroll
    for (int it = 0; it < 4; it++){
      int row = it*32 + w*8 + lrow;
      int csrc = ls ^ (row & 7);               // XOR swizzle: slot s holds chunk s^(row&7)
      __builtin_amdgcn_global_load_lds(
        (const __attribute__((address_space(1))) unsigned*)&A[(size_t)(m0+row)*256 + k0 + csrc*8],
        (__attribute__((address_space(3))) unsigned*)&As[buf][(it*32 + w*8)*64], 16, 0, 0);
      __builtin_amdgcn_global_load_lds(
        (const __attribute__((address_space(1))) unsigned*)&Bt[(size_t)(n0+row)*256 + k0 + csrc*8],
        (__attribute__((address_space(3))) unsigned*)&Bs[buf][(it*32 + w*8)*64], 16, 0, 0);
    }
  };

  STAGE(0, 0);                                  // prologue
  #pragma unroll
  for (int t4 = 0; t4 < 4; t4++){
    if (t4 < 3) STAGE((t4+1)&1, (t4+1)*64);     // prefetch next K-step
    if (t4 < 3) asm volatile("s_waitcnt vmcnt(8)" ::: "memory");  // cur staged; next in flight
    else        asm volatile("s_waitcnt vmcnt(0)" ::: "memory");
    __builtin_amdgcn_s_barrier();               // raw barrier: no forced vmcnt(0) drain
    const unsigned short* Asb = As[t4&1];
    const unsigned short* Bsb = Bs[t4&1];
    #pragma unroll
    for (int ks = 0; ks < 64; ks += 32){
      const int cki = (ks >> 3) + quad;        // k-chunk index 0..7
      short8 af[4], bfr[4];
      #pragma unroll
      for (int i = 0; i < 4; i++){
        int row = wm + i*16 + l15;
        af[i]  = *(const short8*)&Asb[row*64 + (cki ^ (row & 7))*8];
      }
      #pragma unroll
      for (int j = 0; j < 4; j++){
        int row = wn + j*16 + l15;
        bfr[j] = *(const short8*)&Bsb[row*64 + (cki ^ (row & 7))*8];
      }
      #pragma unroll
      for (int i = 0; i < 4; i++)
        #pragma unroll
        for (int j = 0; j < 4; j++)
          acc[i][j] = __builtin_amdgcn_mfma_f32_16x16x32_bf16(af[i], bfr[j], acc[i][j], 0, 0, 0);
    }
    __builtin_amdgcn_s_barrier();               // all waves done reading buf before its re-stage
  }

  if (EPI == 0){
    #pragma unroll
    for (int i = 0; i < 4; i++){
      int mg = m0 + wm + i*16 + quad*4;        // rows mg..mg+3 in this reg quad
      int t = mg >> 6, b = mg & 63;
      #pragma unroll
      for (int j = 0; j < 4; j++){
        int ng = n0 + wn + j*16 + l15;         // n' (gate-interleaved)
        float bb = bias[(ng & 3)*256 + (ng >> 2)];
        f32x4 v = acc[i][j];
        v[0] += bb; v[1] += bb; v[2] += bb; v[3] += bb;
        *(f32x4*)&outZ[((size_t)t*1024 + ng)*64 + b] = v;
      }
    }
  } else {
    #pragma unroll
    for (int i = 0; i < 4; i++){
      float rs[4] = {0.f,0.f,0.f,0.f};
      #pragma unroll
      for (int j = 0; j < 4; j++){
        int ng = n0 + wn + j*16 + l15;
        float bb = bias[ng];
        f32x4 v = acc[i][j];
        #pragma unroll
        for (int r = 0; r < 4; r++){
          float e = v[r] + bb;
          int mloc = wm + i*16 + quad*4 + r;
          if (tgt_s[mloc] == ng) LT[m0 + mloc] = e;
          rs[r] += __expf(e);
        }
      }
      #pragma unroll
      for (int r = 0; r < 4; r++){
        float s = rs[r];
        s += __shfl_xor(s, 1, 16);
        s += __shfl_xor(s, 2, 16);
        s += __shfl_xor(s, 4, 16);
        s += __shfl_xor(s, 8, 16);
        if (l15 == 0) atomicAdd(&S[m0 + wm + i*16 + quad*4 + r], s);
      }
    }
  }
}

// ---- persistent 2-layer LSTM, 24 WGs cooperative, flag-notify dataflow.
// WG 0..7: layer0 (32 units each); WG 8..23: layer1 (16 units each). Weights in regs.
// Protocol per step t: producers store h (agent scope, write-through LLC),
// s_waitcnt(0), __syncthreads, tid0 atomicAdd(flag[t]). Consumers: tid0 spins on a
// single 4B agent load of flag[t] until quorum, then ONE plain global_load_lds bulk
// stage (addresses fresh per t -> no stale-L2 hazard; kernel-start acquire cleared L2).
// [FROZEN this round: verified bit-exact; addressing model not fully reconciled -> no edits]
__launch_bounds__(256, 1)
__global__ void k_lstm(const float* __restrict__ Z0x,          // [128 t][1024 n'][64 b] f32 (b0 folded)
                       const unsigned short* __restrict__ W0h, // [1024 n'][256 k] bf16
                       const unsigned short* __restrict__ W1,  // [1024 n'][512 k] bf16
                       const float* __restrict__ b1,
                       u64* __restrict__ h0h,                  // [128 t][2048] = [kb][b][8] bf16
                       u64* __restrict__ h1h,                  // [128 t][2048]
                       unsigned short* __restrict__ H1bf,      // [b*128+t][256 u]
                       unsigned* __restrict__ flag0,           // [128]
                       unsigned* __restrict__ flag1){          // [128]
  __shared__ __align__(16) char smraw[65536];        // union: h-frag stage | z scratch
  unsigned short* hs = (unsigned short*)smraw;
  float* zl = (float*)smraw;

  const int wg = blockIdx.x;
  const bool L0 = (wg < 8);
  const int tid = threadIdx.x;
  const int w = tid >> 6, l = tid & 63, quad = l >> 4, l15 = l & 15;
  const int b = tid & 63;
  const unsigned short* h0s = (const unsigned short*)h0h;
  const unsigned short* h1s = (const unsigned short*)h1h;

  short8 bw[16];               // persistent weight fragments (64 VGPRs)
  float c_st[8];
  float b1r[16];
  #pragma unroll
  for (int i = 0; i < 8; i++) c_st[i] = 0.f;

  if (L0){
    const int n0 = wg*128;
    #pragma unroll
    for (int j = 0; j < 2; j++)
      #pragma unroll
      for (int ks = 0; ks < 8; ks++)
        bw[j*8+ks] = *(const short8*)&W0h[(size_t)(n0 + w*32 + j*16 + l15)*256 + ks*32 + quad*8];
  } else {
    const int n0 = (wg-8)*64;
    #pragma unroll
    for (int ks = 0; ks < 16; ks++)
      bw[ks] = *(const short8*)&W1[(size_t)(n0 + w*16 + l15)*512 + ks*32 + quad*8];
    const int u0 = (wg-8)*16, ul0 = w*4;
    #pragma unroll
    for (int ul = 0; ul < 4; ul++)
      #pragma unroll
      for (int g = 0; g < 4; g++)
        b1r[ul*4+g] = b1[g*256 + u0 + ul0 + ul];
  }

  if (L0){
    const int n0 = wg*128;
    for (int t = 0; t < 128; t++){
      f32x4 acc[4][2];
      #pragma unroll
      for (int i = 0; i < 4; i++)
        #pragma unroll
        for (int j = 0; j < 2; j++){
          int cl = w*32 + j*16 + l15;
          acc[i][j] = *(const f32x4*)&Z0x[((size_t)t*1024 + n0 + cl)*64 + i*16 + quad*4];
        }
      if (t > 0){
        if (tid == 0)
          while (__hip_atomic_load(flag0 + (t-1), __ATOMIC_RELAXED, __HIP_MEMORY_SCOPE_AGENT) < 8u)
            __builtin_amdgcn_s_sleep(1);
        __syncthreads();
        #pragma unroll
        for (int it = 0; it < 8; it++){
          int c = it*256 + w*64 + l;
          __builtin_amdgcn_global_load_lds(
            (const __attribute__((address_space(1))) unsigned*)&h0s[(size_t)(t-1)*16384 + (size_t)c*8],
            (__attribute__((address_space(3))) unsigned*)&hs[(it*256 + w*64)*8], 16, 0, 0);
        }
        __builtin_amdgcn_s_waitcnt(0);
        __syncthreads();
        #pragma unroll
        for (int ks = 0; ks < 8; ks++){
          short8 a[4];
          #pragma unroll
          for (int i = 0; i < 4; i++)
            a[i] = *(const short8*)&hs[(((ks*4+quad)*64) + i*16 + l15)*8];
          #pragma unroll
          for (int i = 0; i < 4; i++)
            #pragma unroll
            for (int j = 0; j < 2; j++)
              acc[i][j] = __builtin_amdgcn_mfma_f32_16x16x32_bf16(a[i], bw[j*8+ks], acc[i][j], 0, 0, 0);
        }
        __syncthreads();                       // hs reads done; zl aliases hs
      }
      #pragma unroll
      for (int i = 0; i < 4; i++)
        #pragma unroll
        for (int j = 0; j < 2; j++){
          int cl = w*32 + j*16 + l15;
          *(f32x4*)&zl[cl*68 + i*16 + quad*4] = acc[i][j];
        }
      __syncthreads();
      // cell update: 8 units per thread
      const int ul0 = w*8;
      unsigned short hout[8];
      #pragma unroll
      for (int ui = 0; ui < 8; ui++){
        int cc = (ul0 + ui)*4;
        float zi = zl[(cc+0)*68 + b], zj = zl[(cc+1)*68 + b];
        float zf = zl[(cc+2)*68 + b], zo = zl[(cc+3)*68 + b];
        float c = c_st[ui]*sigm(zf + 1.0f) + sigm(zi)*tanh_(zj);
        c_st[ui] = c;
        hout[ui] = f2b(tanh_(c)*sigm(zo));
      }
      // publish (agent scope -> LLC write-through), then notify
      {
        u64 v0 = (u64)pk2(hout[0],hout[1]) | ((u64)pk2(hout[2],hout[3]) << 32);
        u64 v1 = (u64)pk2(hout[4],hout[5]) | ((u64)pk2(hout[6],hout[7]) << 32);
        size_t pbase = (size_t)t*2048 + ((size_t)(wg*4 + w)*64 + b)*2;
        __hip_atomic_store(h0h + pbase,     v0, __ATOMIC_RELAXED, __HIP_MEMORY_SCOPE_AGENT);
        __hip_atomic_store(h0h + pbase + 1, v1, __ATOMIC_RELAXED, __HIP_MEMORY_SCOPE_AGENT);
      }
      __builtin_amdgcn_s_waitcnt(0);           // stores LLC-acked
      __syncthreads();                         // all threads' stores acked; zl reads done
      if (tid == 0)
        __hip_atomic_fetch_add(flag0 + t, 1u, __ATOMIC_RELAXED, __HIP_MEMORY_SCOPE_AGENT);
    }
  } else {
    const int u0 = (wg-8)*16, ul0 = w*4;
    for (int t = 0; t < 128; t++){
      f32x4 acc[4];
      #pragma unroll
      for (int i = 0; i < 4; i++) acc[i] = (f32x4){0.f,0.f,0.f,0.f};
      if (t > 0){
        // h1(t-1): ready (we produced it); stage + MFMA its half while layer0 works on h0(t)
        if (tid == 0)
          while (__hip_atomic_load(flag1 + (t-1), __ATOMIC_RELAXED, __HIP_MEMORY_SCOPE_AGENT) < 16u)
            __builtin_amdgcn_s_sleep(1);
        __syncthreads();
        #pragma unroll
        for (int it = 0; it < 8; it++){
          int c = it*256 + w*64 + l;
          __builtin_amdgcn_global_load_lds(
            (const __attribute__((address_space(1))) unsigned*)&h1s[(size_t)(t-1)*16384 + (size_t)c*8],
            (__attribute__((address_space(3))) unsigned*)&hs[16384 + (it*256 + w*64)*8], 16, 0, 0);
        }
        __builtin_amdgcn_s_waitcnt(0);
        __syncthreads();
        #pragma unroll
        for (int ks = 8; ks < 16; ks++){       // kb 32..63 -> hs shorts 16384..32767
          short8 a[4];
          #pragma unroll
          for (int i = 0; i < 4; i++)
            a[i] = *(const short8*)&hs[(((ks*4+quad)*64) + i*16 + l15)*8];
          #pragma unroll
          for (int i = 0; i < 4; i++)
            acc[i] = __builtin_amdgcn_mfma_f32_16x16x32_bf16(a[i], bw[ks], acc[i], 0, 0, 0);
        }
      }
      // critical h0(t)
      if (tid == 0)
        while (__hip_atomic_load(flag0 + t, __ATOMIC_RELAXED, __HIP_MEMORY_SCOPE_AGENT) < 8u)
          __builtin_amdgcn_s_sleep(1);
      __syncthreads();
      #pragma unroll
      for (int it = 0; it < 8; it++){
        int c = it*256 + w*64 + l;
        __builtin_amdgcn_global_load_lds(
          (const __attribute__((address_space(1))) unsigned*)&h0s[(size_t)t*16384 + (size_t)c*8],
          (__attribute__((address_space(3))) unsigned*)&hs[(it*256 + w*64)*8], 16, 0, 0);
      }
      __builtin_amdgcn_s_waitcnt(0);
      __syncthreads();
      #pragma unroll
      for (int ks = 0; ks < 8; ks++){
        short8 a[4];
        #pragma unroll
        for (int i = 0; i < 4; i++)
          a[i] = *(const short8*)&hs[(((ks*4+quad)*64) + i*16 + l15)*8];
        #pragma unroll
        for (int i = 0; i < 4; i++)
          acc[i] = __builtin_amdgcn_mfma_f32_16x16x32_bf16(a[i], bw[ks], acc[i], 0, 0, 0);
      }
      __syncthreads();                         // hs reads done; zl aliases hs
      {
        int cl = w*16 + l15;
        #pragma unroll
        for (int i = 0; i < 4; i++)
          *(f32x4*)&zl[cl*68 + i*16 + quad*4] = acc[i];
      }
      __syncthreads();
      // cell update: 4 units per thread
      unsigned short hout[4];
      #pragma unroll
      for (int ui = 0; ui < 4; ui++){
        int cc = (ul0 + ui)*4;
        float zi = zl[(cc+0)*68 + b] + b1r[ui*4+0];
        float zj = zl[(cc+1)*68 + b] + b1r[ui*4+1];
        float zf = zl[(cc+2)*68 + b] + b1r[ui*4+2];
        float zo = zl[(cc+3)*68 + b] + b1r[ui*4+3];
        float c = c_st[ui]*sigm(zf + 1.0f) + sigm(zi)*tanh_(zj);
        c_st[ui] = c;
        hout[ui] = f2b(tanh_(c)*sigm(zo));
      }
      {
        const int u = u0 + ul0;                // multiple of 4
        u64 v = (u64)pk2(hout[0],hout[1]) | ((u64)pk2(hout[2],hout[3]) << 32);
        size_t pbase = (size_t)t*2048 + ((size_t)(u >> 3)*64 + b)*2 + ((u & 4) >> 2);
        __hip_atomic_store(h1h + pbase, v, __ATOMIC_RELAXED, __HIP_MEMORY_SCOPE_AGENT);
        *(uint2*)&H1bf[((size_t)b*128 + t)*256 + u] = *(const uint2*)hout;   // plain store
      }
      __builtin_amdgcn_s_waitcnt(0);
      __syncthreads();
      if (tid == 0)
        __hip_atomic_fetch_add(flag1 + t, 1u, __ATOMIC_RELAXED, __HIP_MEMORY_SCOPE_AGENT);
    }
  }
}

// ---- final reduce: cost = mean(log(S) - LT)
__global__ void k_reduce(const float* __restrict__ S, const float* __restrict__ LT,
                         float* __restrict__ out){
  __shared__ float red[256];
  float s = 0.f;
  for (int r = threadIdx.x; r < 8192; r += 256) s += __logf(S[r]) - LT[r];
  red[threadIdx.x] = s;
  __syncthreads();
  for (int st = 128; st > 0; st >>= 1){
    if (threadIdx.x < st) red[threadIdx.x] += red[threadIdx.x + st];
    __syncthreads();
  }
  if (threadIdx.x == 0) out[0] = red[0] / 8192.0f;
}

extern "C" void kernel_launch(void* const* d_in, const int* in_sizes, int n_in,
                              void* d_out, int out_size, void* d_ws, size_t ws_size,
                              hipStream_t stream){
  const int*   input   = (const int*)  d_in[0];
  const int*   targets = (const int*)  d_in[1];
  const float* emb     = (const float*)d_in[2];
  const float* W0      = (const float*)d_in[3];
  const float* b0      = (const float*)d_in[4];
  const float* W1      = (const float*)d_in[5];
  const float* b1      = (const float*)d_in[6];
  const float* Wsm     = (const float*)d_in[7];
  const float* sb      = (const float*)d_in[8];

  char* ws = (char*)d_ws;
  size_t off = 0;
  auto alloc = [&](size_t bytes)->char*{
    char* p = ws + off; off += (bytes + 255) & ~(size_t)255; return p;
  };
  unsigned short* Xbf  = (unsigned short*)alloc(8192ull*256*2);
  unsigned short* W0xT = (unsigned short*)alloc(1024ull*256*2);
  unsigned short* W0hT = (unsigned short*)alloc(1024ull*256*2);
  unsigned short* W1T  = (unsigned short*)alloc(1024ull*512*2);
  unsigned short* WsT  = (unsigned short*)alloc(16000ull*256*2);
  float*          Z0x  = (float*)         alloc(8192ull*1024*4);
  u64*            h0h  = (u64*)           alloc(128ull*2048*8);   // h0 history [t][kb][b][8]
  u64*            h1h  = (u64*)           alloc(128ull*2048*8);
  unsigned short* H1bf = (unsigned short*)alloc(8192ull*256*2);
  float*          S    = (float*)         alloc(8192ull*4);
  float*          LT   = (float*)         alloc(8192ull*4);
  unsigned*       flag0= (unsigned*)      alloc(128*4);
  unsigned*       flag1= (unsigned*)      alloc(128*4);

  hipMemsetAsync(S,     0, 8192ull*4, stream);
  hipMemsetAsync(flag0, 0, 2*((128*4 + 255) & ~255), stream);  // flag0+flag1 contiguous

  k_gather<<<dim3(8192), dim3(256), 0, stream>>>(input, emb, Xbf);
  k_transpose<1,1><<<dim3(32, 8),  dim3(32,8), 0, stream>>>(W0,  (void*)W0xT, 256, 1024, 1024, 0);
  k_transpose<1,1><<<dim3(32, 8),  dim3(32,8), 0, stream>>>(W0,  (void*)W0hT, 256, 1024, 1024, 256);
  k_transpose<1,1><<<dim3(32, 16), dim3(32,8), 0, stream>>>(W1,  (void*)W1T,  512, 1024, 1024, 0);
  k_transpose<1,0><<<dim3(500, 8), dim3(32,8), 0, stream>>>(Wsm, (void*)WsT,  256, 16000, 16000, 0);

  // Z0x = X @ W0[:256,:] + b0   (M=8192 r'=(t,b), N=1024 n', K=256); m-major blocks
  k_gemm<0><<<dim3(64, 8), dim3(256), 0, stream>>>(Xbf, W0xT, Z0x, b0, nullptr, nullptr, nullptr);

  // persistent LSTM (24 WGs cooperative; flag-notify dataflow)
  void* kargs[] = { (void*)&Z0x, (void*)&W0hT, (void*)&W1T, (void*)&b1,
                    (void*)&h0h, (void*)&h1h, (void*)&H1bf, (void*)&flag0, (void*)&flag1 };
  hipLaunchCooperativeKernel((void*)k_lstm, dim3(24), dim3(256), kargs, 0, stream);

  // fused projection + log-softmax partials (M=8192 r=(b,t), N=16000, K=256); m-major blocks
  k_gemm<1><<<dim3(64, 125), dim3(256), 0, stream>>>(H1bf, WsT, nullptr, sb, targets, S, LT);

  k_reduce<<<dim3(1), dim3(256), 0, stream>>>(S, LT, (float*)d_out);
}

// Round 7
// 888.290 us; speedup vs baseline: 1.0104x; 1.0104x over previous
//
#include <hip/hip_runtime.h>
#include <hip/hip_bf16.h>
#include <stdint.h>

typedef __attribute__((ext_vector_type(8))) short short8;
typedef __attribute__((ext_vector_type(4))) float f32x4;
typedef unsigned long long u64;

#define DI static __device__ __forceinline__

DI unsigned short f2b(float f){
  unsigned u = __float_as_uint(f);
  u = (u + 0x7FFFu + ((u >> 16) & 1u)) >> 16;
  return (unsigned short)u;
}
DI float sigm(float x){ return 1.0f / (1.0f + __expf(-x)); }
DI float tanh_(float x){ return 1.0f - 2.0f / (__expf(2.0f*x) + 1.0f); } // safe at +/-inf
DI unsigned pk2(unsigned short a, unsigned short b){ return (unsigned)a | ((unsigned)b << 16); }

// ---- embedding gather: Xbf[r' = t*64+b][256] = bf16(emb[input[b][t]])
__global__ void k_gather(const int* __restrict__ inp, const float* __restrict__ emb,
                         unsigned short* __restrict__ Xbf){
  int r = blockIdx.x;            // r' = t*64 + b
  int t = r >> 6, b = r & 63;
  int idx = inp[b*128 + t];
  float v = emb[(size_t)idx*256 + threadIdx.x];
  Xbf[(size_t)r*256 + threadIdx.x] = f2b(v);
}

// ---- transpose src[R][C] (rows row0..row0+R-1, ld) -> dst[n(C)][R]
// BF: bf16 output. REORD: gate-interleave columns n' = (c&255)*4 + (c>>8)
template<int BF, int REORD>
__global__ void k_transpose(const float* __restrict__ src, void* __restrict__ dst,
                            int R, int C, int ld, int row0){
  __shared__ float tile[32][33];
  int tx = threadIdx.x, ty = threadIdx.y;
  int x = blockIdx.x*32 + tx;
  for (int i = 0; i < 4; i++){
    int y = blockIdx.y*32 + ty + i*8;
    if (x < C && y < R) tile[ty + i*8][tx] = src[(size_t)(row0 + y)*ld + x];
  }
  __syncthreads();
  int y2 = blockIdx.y*32 + tx;                 // R index
  for (int i = 0; i < 4; i++){
    int x2 = blockIdx.x*32 + ty + i*8;         // C index
    if (x2 < C && y2 < R){
      float v = tile[tx][ty + i*8];
      int n = REORD ? ((x2 & 255)*4 + (x2 >> 8)) : x2;
      if (BF) ((unsigned short*)dst)[(size_t)n*R + y2] = f2b(v);
      else    ((float*)dst)[(size_t)n*R + y2] = v;
    }
  }
}

// ---- MFMA GEMM (verified m97 single-buffer pattern) — used for EPI0 (Z0x).
// C[m][n] = sum_k A[m][k]*Bt[n][k], A/Bt bf16 [rows][256].
template<int EPI>
__launch_bounds__(256, 2)
__global__ void k_gemm(const unsigned short* __restrict__ A, const unsigned short* __restrict__ Bt,
                       float* __restrict__ outZ, const float* __restrict__ bias,
                       const int* __restrict__ tgt, float* __restrict__ S, float* __restrict__ LT){
  __shared__ unsigned short As[128*64];
  __shared__ unsigned short Bs[128*64];
  __shared__ int tgt_s[128];
  const int m0 = blockIdx.x*128, n0 = blockIdx.y*128;
  const int tid = threadIdx.x;
  const int w = tid >> 6, l = tid & 63;
  const int quad = l >> 4, l15 = l & 15;
  const int wm = (w >> 1)*64, wn = (w & 1)*64;
  const int lrow = l >> 3, ls = l & 7;         // lane -> (row-in-group, slot)
  f32x4 acc[4][4] = {};
  if (EPI == 1 && tid < 128) tgt_s[tid] = tgt[m0 + tid];

  for (int k0 = 0; k0 < 256; k0 += 64){
    #pragma unroll
    for (int it = 0; it < 4; it++){
      int row = it*32 + w*8 + lrow;
      int csrc = ls ^ (row & 7);               // XOR swizzle: slot s holds chunk s^(row&7)
      __builtin_amdgcn_global_load_lds(
        (const __attribute__((address_space(1))) unsigned*)&A[(size_t)(m0+row)*256 + k0 + csrc*8],
        (__attribute__((address_space(3))) unsigned*)&As[(it*32 + w*8)*64], 16, 0, 0);
      __builtin_amdgcn_global_load_lds(
        (const __attribute__((address_space(1))) unsigned*)&Bt[(size_t)(n0+row)*256 + k0 + csrc*8],
        (__attribute__((address_space(3))) unsigned*)&Bs[(it*32 + w*8)*64], 16, 0, 0);
    }
    __syncthreads();
    #pragma unroll
    for (int ks = 0; ks < 64; ks += 32){
      const int cki = (ks >> 3) + quad;        // k-chunk index 0..7
      short8 af[4], bfr[4];
      #pragma unroll
      for (int i = 0; i < 4; i++){
        int row = wm + i*16 + l15;
        af[i]  = *(short8*)&As[row*64 + (cki ^ (row & 7))*8];
      }
      #pragma unroll
      for (int j = 0; j < 4; j++){
        int row = wn + j*16 + l15;
        bfr[j] = *(short8*)&Bs[row*64 + (cki ^ (row & 7))*8];
      }
      #pragma unroll
      for (int i = 0; i < 4; i++)
        #pragma unroll
        for (int j = 0; j < 4; j++)
          acc[i][j] = __builtin_amdgcn_mfma_f32_16x16x32_bf16(af[i], bfr[j], acc[i][j], 0, 0, 0);
    }
    __syncthreads();
  }

  if (EPI == 0){
    #pragma unroll
    for (int i = 0; i < 4; i++){
      int mg = m0 + wm + i*16 + quad*4;        // rows mg..mg+3 in this reg quad
      int t = mg >> 6, b = mg & 63;
      #pragma unroll
      for (int j = 0; j < 4; j++){
        int ng = n0 + wn + j*16 + l15;         // n' (gate-interleaved)
        float bb = bias[(ng & 3)*256 + (ng >> 2)];
        f32x4 v = acc[i][j];
        v[0] += bb; v[1] += bb; v[2] += bb; v[3] += bb;
        *(f32x4*)&outZ[((size_t)t*1024 + ng)*64 + b] = v;
      }
    }
  } else {
    #pragma unroll
    for (int i = 0; i < 4; i++){
      float rs[4] = {0.f,0.f,0.f,0.f};
      #pragma unroll
      for (int j = 0; j < 4; j++){
        int ng = n0 + wn + j*16 + l15;
        float bb = bias[ng];
        f32x4 v = acc[i][j];
        #pragma unroll
        for (int r = 0; r < 4; r++){
          float e = v[r] + bb;
          int mloc = wm + i*16 + quad*4 + r;
          if (tgt_s[mloc] == ng) LT[m0 + mloc] = e;
          rs[r] += __expf(e);
        }
      }
      #pragma unroll
      for (int r = 0; r < 4; r++){
        float s = rs[r];
        s += __shfl_xor(s, 1, 16);
        s += __shfl_xor(s, 2, 16);
        s += __shfl_xor(s, 4, 16);
        s += __shfl_xor(s, 8, 16);
        if (l15 == 0) atomicAdd(&S[m0 + wm + i*16 + quad*4 + r], s);
      }
    }
  }
}

// ---- projection GEMM, dual-m tile (256 m-rows x 128 n-cols per block):
// same verified m97 staging idiom (syncthreads drain, XOR swizzle, single buffer),
// but the B-panel is staged ONCE per K-step and consumed by TWO A-tiles ->
// B-staging per output element halves, per-phase MFMA density doubles (32 vs 16).
// Fused softmax partial epilogue: S[row] += sum exp(logit+bias); LT[row] = logit_tgt.
__launch_bounds__(256, 2)
__global__ void k_gemm2(const unsigned short* __restrict__ A, const unsigned short* __restrict__ Bt,
                        const float* __restrict__ bias, const int* __restrict__ tgt,
                        float* __restrict__ S, float* __restrict__ LT){
  __shared__ unsigned short As[256*64];        // 32KB: two 128-row m-tiles
  __shared__ unsigned short Bs[128*64];        // 16KB
  __shared__ int tgt_s[256];
  const int m0 = blockIdx.x*256, n0 = blockIdx.y*128;
  const int tid = threadIdx.x;
  const int w = tid >> 6, l = tid & 63;
  const int quad = l >> 4, l15 = l & 15;
  const int wm = (w >> 1)*64, wn = (w & 1)*64;
  const int lrow = l >> 3, ls = l & 7;         // lane -> (row-in-group, slot)
  f32x4 acc[8][4] = {};                        // i: (i>>2)=m-half, (i&3)=16-row group
  tgt_s[tid] = tgt[m0 + tid];

  for (int k0 = 0; k0 < 256; k0 += 64){
    #pragma unroll
    for (int it = 0; it < 8; it++){            // A: 256 rows
      int row = it*32 + w*8 + lrow;
      int csrc = ls ^ (row & 7);
      __builtin_amdgcn_global_load_lds(
        (const __attribute__((address_space(1))) unsigned*)&A[(size_t)(m0+row)*256 + k0 + csrc*8],
        (__attribute__((address_space(3))) unsigned*)&As[(it*32 + w*8)*64], 16, 0, 0);
    }
    #pragma unroll
    for (int it = 0; it < 4; it++){            // B: 128 rows
      int row = it*32 + w*8 + lrow;
      int csrc = ls ^ (row & 7);
      __builtin_amdgcn_global_load_lds(
        (const __attribute__((address_space(1))) unsigned*)&Bt[(size_t)(n0+row)*256 + k0 + csrc*8],
        (__attribute__((address_space(3))) unsigned*)&Bs[(it*32 + w*8)*64], 16, 0, 0);
    }
    __syncthreads();                           // compiler drain: staging complete
    #pragma unroll
    for (int ks = 0; ks < 64; ks += 32){
      const int cki = (ks >> 3) + quad;        // k-chunk index 0..7
      short8 af[8], bfr[4];
      #pragma unroll
      for (int i = 0; i < 8; i++){
        int row = (i >> 2)*128 + wm + (i & 3)*16 + l15;
        af[i]  = *(const short8*)&As[row*64 + (cki ^ (row & 7))*8];
      }
      #pragma unroll
      for (int j = 0; j < 4; j++){
        int row = wn + j*16 + l15;
        bfr[j] = *(const short8*)&Bs[row*64 + (cki ^ (row & 7))*8];
      }
      #pragma unroll
      for (int i = 0; i < 8; i++)
        #pragma unroll
        for (int j = 0; j < 4; j++)
          acc[i][j] = __builtin_amdgcn_mfma_f32_16x16x32_bf16(af[i], bfr[j], acc[i][j], 0, 0, 0);
    }
    __syncthreads();                           // all reads done before buffer re-stage
  }

  #pragma unroll
  for (int i = 0; i < 8; i++){
    const int mbase = (i >> 2)*128 + wm + (i & 3)*16 + quad*4;
    float rs[4] = {0.f,0.f,0.f,0.f};
    #pragma unroll
    for (int j = 0; j < 4; j++){
      int ng = n0 + wn + j*16 + l15;
      float bb = bias[ng];
      f32x4 v = acc[i][j];
      #pragma unroll
      for (int r = 0; r < 4; r++){
        float e = v[r] + bb;
        if (tgt_s[mbase + r] == ng) LT[m0 + mbase + r] = e;
        rs[r] += __expf(e);
      }
    }
    #pragma unroll
    for (int r = 0; r < 4; r++){
      float s = rs[r];
      s += __shfl_xor(s, 1, 16);
      s += __shfl_xor(s, 2, 16);
      s += __shfl_xor(s, 4, 16);
      s += __shfl_xor(s, 8, 16);
      if (l15 == 0) atomicAdd(&S[m0 + mbase + r], s);
    }
  }
}

// ---- persistent 2-layer LSTM, 24 WGs cooperative, flag-notify dataflow.
// WG 0..7: layer0 (32 units each); WG 8..23: layer1 (16 units each). Weights in regs.
// Protocol per step t: producers store h (agent scope, write-through LLC),
// s_waitcnt(0), __syncthreads, tid0 atomicAdd(flag[t]). Consumers: tid0 spins on a
// single 4B agent load of flag[t] until quorum, then ONE plain global_load_lds bulk
// stage (addresses fresh per t -> no stale-L2 hazard; kernel-start acquire cleared L2).
// [FROZEN: verified bit-exact across 3 runs; no edits without isolating counters]
__launch_bounds__(256, 1)
__global__ void k_lstm(const float* __restrict__ Z0x,          // [128 t][1024 n'][64 b] f32 (b0 folded)
                       const unsigned short* __restrict__ W0h, // [1024 n'][256 k] bf16
                       const unsigned short* __restrict__ W1,  // [1024 n'][512 k] bf16
                       const float* __restrict__ b1,
                       u64* __restrict__ h0h,                  // [128 t][2048] = [kb][b][8] bf16
                       u64* __restrict__ h1h,                  // [128 t][2048]
                       unsigned short* __restrict__ H1bf,      // [b*128+t][256 u]
                       unsigned* __restrict__ flag0,           // [128]
                       unsigned* __restrict__ flag1){          // [128]
  __shared__ __align__(16) char smraw[65536];        // union: h-frag stage | z scratch
  unsigned short* hs = (unsigned short*)smraw;
  float* zl = (float*)smraw;

  const int wg = blockIdx.x;
  const bool L0 = (wg < 8);
  const int tid = threadIdx.x;
  const int w = tid >> 6, l = tid & 63, quad = l >> 4, l15 = l & 15;
  const int b = tid & 63;
  const unsigned short* h0s = (const unsigned short*)h0h;
  const unsigned short* h1s = (const unsigned short*)h1h;

  short8 bw[16];               // persistent weight fragments (64 VGPRs)
  float c_st[8];
  float b1r[16];
  #pragma unroll
  for (int i = 0; i < 8; i++) c_st[i] = 0.f;

  if (L0){
    const int n0 = wg*128;
    #pragma unroll
    for (int j = 0; j < 2; j++)
      #pragma unroll
      for (int ks = 0; ks < 8; ks++)
        bw[j*8+ks] = *(const short8*)&W0h[(size_t)(n0 + w*32 + j*16 + l15)*256 + ks*32 + quad*8];
  } else {
    const int n0 = (wg-8)*64;
    #pragma unroll
    for (int ks = 0; ks < 16; ks++)
      bw[ks] = *(const short8*)&W1[(size_t)(n0 + w*16 + l15)*512 + ks*32 + quad*8];
    const int u0 = (wg-8)*16, ul0 = w*4;
    #pragma unroll
    for (int ul = 0; ul < 4; ul++)
      #pragma unroll
      for (int g = 0; g < 4; g++)
        b1r[ul*4+g] = b1[g*256 + u0 + ul0 + ul];
  }

  if (L0){
    const int n0 = wg*128;
    for (int t = 0; t < 128; t++){
      f32x4 acc[4][2];
      #pragma unroll
      for (int i = 0; i < 4; i++)
        #pragma unroll
        for (int j = 0; j < 2; j++){
          int cl = w*32 + j*16 + l15;
          acc[i][j] = *(const f32x4*)&Z0x[((size_t)t*1024 + n0 + cl)*64 + i*16 + quad*4];
        }
      if (t > 0){
        if (tid == 0)
          while (__hip_atomic_load(flag0 + (t-1), __ATOMIC_RELAXED, __HIP_MEMORY_SCOPE_AGENT) < 8u)
            __builtin_amdgcn_s_sleep(1);
        __syncthreads();
        #pragma unroll
        for (int it = 0; it < 8; it++){
          int c = it*256 + w*64 + l;
          __builtin_amdgcn_global_load_lds(
            (const __attribute__((address_space(1))) unsigned*)&h0s[(size_t)(t-1)*16384 + (size_t)c*8],
            (__attribute__((address_space(3))) unsigned*)&hs[(it*256 + w*64)*8], 16, 0, 0);
        }
        __builtin_amdgcn_s_waitcnt(0);
        __syncthreads();
        #pragma unroll
        for (int ks = 0; ks < 8; ks++){
          short8 a[4];
          #pragma unroll
          for (int i = 0; i < 4; i++)
            a[i] = *(const short8*)&hs[(((ks*4+quad)*64) + i*16 + l15)*8];
          #pragma unroll
          for (int i = 0; i < 4; i++)
            #pragma unroll
            for (int j = 0; j < 2; j++)
              acc[i][j] = __builtin_amdgcn_mfma_f32_16x16x32_bf16(a[i], bw[j*8+ks], acc[i][j], 0, 0, 0);
        }
        __syncthreads();                       // hs reads done; zl aliases hs
      }
      #pragma unroll
      for (int i = 0; i < 4; i++)
        #pragma unroll
        for (int j = 0; j < 2; j++){
          int cl = w*32 + j*16 + l15;
          *(f32x4*)&zl[cl*68 + i*16 + quad*4] = acc[i][j];
        }
      __syncthreads();
      // cell update: 8 units per thread
      const int ul0 = w*8;
      unsigned short hout[8];
      #pragma unroll
      for (int ui = 0; ui < 8; ui++){
        int cc = (ul0 + ui)*4;
        float zi = zl[(cc+0)*68 + b], zj = zl[(cc+1)*68 + b];
        float zf = zl[(cc+2)*68 + b], zo = zl[(cc+3)*68 + b];
        float c = c_st[ui]*sigm(zf + 1.0f) + sigm(zi)*tanh_(zj);
        c_st[ui] = c;
        hout[ui] = f2b(tanh_(c)*sigm(zo));
      }
      // publish (agent scope -> LLC write-through), then notify
      {
        u64 v0 = (u64)pk2(hout[0],hout[1]) | ((u64)pk2(hout[2],hout[3]) << 32);
        u64 v1 = (u64)pk2(hout[4],hout[5]) | ((u64)pk2(hout[6],hout[7]) << 32);
        size_t pbase = (size_t)t*2048 + ((size_t)(wg*4 + w)*64 + b)*2;
        __hip_atomic_store(h0h + pbase,     v0, __ATOMIC_RELAXED, __HIP_MEMORY_SCOPE_AGENT);
        __hip_atomic_store(h0h + pbase + 1, v1, __ATOMIC_RELAXED, __HIP_MEMORY_SCOPE_AGENT);
      }
      __builtin_amdgcn_s_waitcnt(0);           // stores LLC-acked
      __syncthreads();                         // all threads' stores acked; zl reads done
      if (tid == 0)
        __hip_atomic_fetch_add(flag0 + t, 1u, __ATOMIC_RELAXED, __HIP_MEMORY_SCOPE_AGENT);
    }
  } else {
    const int u0 = (wg-8)*16, ul0 = w*4;
    for (int t = 0; t < 128; t++){
      f32x4 acc[4];
      #pragma unroll
      for (int i = 0; i < 4; i++) acc[i] = (f32x4){0.f,0.f,0.f,0.f};
      if (t > 0){
        // h1(t-1): ready (we produced it); stage + MFMA its half while layer0 works on h0(t)
        if (tid == 0)
          while (__hip_atomic_load(flag1 + (t-1), __ATOMIC_RELAXED, __HIP_MEMORY_SCOPE_AGENT) < 16u)
            __builtin_amdgcn_s_sleep(1);
        __syncthreads();
        #pragma unroll
        for (int it = 0; it < 8; it++){
          int c = it*256 + w*64 + l;
          __builtin_amdgcn_global_load_lds(
            (const __attribute__((address_space(1))) unsigned*)&h1s[(size_t)(t-1)*16384 + (size_t)c*8],
            (__attribute__((address_space(3))) unsigned*)&hs[16384 + (it*256 + w*64)*8], 16, 0, 0);
        }
        __builtin_amdgcn_s_waitcnt(0);
        __syncthreads();
        #pragma unroll
        for (int ks = 8; ks < 16; ks++){       // kb 32..63 -> hs shorts 16384..32767
          short8 a[4];
          #pragma unroll
          for (int i = 0; i < 4; i++)
            a[i] = *(const short8*)&hs[(((ks*4+quad)*64) + i*16 + l15)*8];
          #pragma unroll
          for (int i = 0; i < 4; i++)
            acc[i] = __builtin_amdgcn_mfma_f32_16x16x32_bf16(a[i], bw[ks], acc[i], 0, 0, 0);
        }
      }
      // critical h0(t)
      if (tid == 0)
        while (__hip_atomic_load(flag0 + t, __ATOMIC_RELAXED, __HIP_MEMORY_SCOPE_AGENT) < 8u)
          __builtin_amdgcn_s_sleep(1);
      __syncthreads();
      #pragma unroll
      for (int it = 0; it < 8; it++){
        int c = it*256 + w*64 + l;
        __builtin_amdgcn_global_load_lds(
          (const __attribute__((address_space(1))) unsigned*)&h0s[(size_t)t*16384 + (size_t)c*8],
          (__attribute__((address_space(3))) unsigned*)&hs[(it*256 + w*64)*8], 16, 0, 0);
      }
      __builtin_amdgcn_s_waitcnt(0);
      __syncthreads();
      #pragma unroll
      for (int ks = 0; ks < 8; ks++){
        short8 a[4];
        #pragma unroll
        for (int i = 0; i < 4; i++)
          a[i] = *(const short8*)&hs[(((ks*4+quad)*64) + i*16 + l15)*8];
        #pragma unroll
        for (int i = 0; i < 4; i++)
          acc[i] = __builtin_amdgcn_mfma_f32_16x16x32_bf16(a[i], bw[ks], acc[i], 0, 0, 0);
      }
      __syncthreads();                         // hs reads done; zl aliases hs
      {
        int cl = w*16 + l15;
        #pragma unroll
        for (int i = 0; i < 4; i++)
          *(f32x4*)&zl[cl*68 + i*16 + quad*4] = acc[i];
      }
      __syncthreads();
      // cell update: 4 units per thread
      unsigned short hout[4];
      #pragma unroll
      for (int ui = 0; ui < 4; ui++){
        int cc = (ul0 + ui)*4;
        float zi = zl[(cc+0)*68 + b] + b1r[ui*4+0];
        float zj = zl[(cc+1)*68 + b] + b1r[ui*4+1];
        float zf = zl[(cc+2)*68 + b] + b1r[ui*4+2];
        float zo = zl[(cc+3)*68 + b] + b1r[ui*4+3];
        float c = c_st[ui]*sigm(zf + 1.0f) + sigm(zi)*tanh_(zj);
        c_st[ui] = c;
        hout[ui] = f2b(tanh_(c)*sigm(zo));
      }
      {
        const int u = u0 + ul0;                // multiple of 4
        u64 v = (u64)pk2(hout[0],hout[1]) | ((u64)pk2(hout[2],hout[3]) << 32);
        size_t pbase = (size_t)t*2048 + ((size_t)(u >> 3)*64 + b)*2 + ((u & 4) >> 2);
        __hip_atomic_store(h1h + pbase, v, __ATOMIC_RELAXED, __HIP_MEMORY_SCOPE_AGENT);
        *(uint2*)&H1bf[((size_t)b*128 + t)*256 + u] = *(const uint2*)hout;   // plain store
      }
      __builtin_amdgcn_s_waitcnt(0);
      __syncthreads();
      if (tid == 0)
        __hip_atomic_fetch_add(flag1 + t, 1u, __ATOMIC_RELAXED, __HIP_MEMORY_SCOPE_AGENT);
    }
  }
}

// ---- final reduce: cost = mean(log(S) - LT), 32 blocks + one atomic each
__global__ void k_reduce(const float* __restrict__ S, const float* __restrict__ LT,
                         float* __restrict__ out){
  __shared__ float red[256];
  int r = blockIdx.x*256 + threadIdx.x;
  red[threadIdx.x] = __logf(S[r]) - LT[r];
  __syncthreads();
  for (int st = 128; st > 0; st >>= 1){
    if (threadIdx.x < st) red[threadIdx.x] += red[threadIdx.x + st];
    __syncthreads();
  }
  if (threadIdx.x == 0) atomicAdd(out, red[0] / 8192.0f);
}

extern "C" void kernel_launch(void* const* d_in, const int* in_sizes, int n_in,
                              void* d_out, int out_size, void* d_ws, size_t ws_size,
                              hipStream_t stream){
  const int*   input   = (const int*)  d_in[0];
  const int*   targets = (const int*)  d_in[1];
  const float* emb     = (const float*)d_in[2];
  const float* W0      = (const float*)d_in[3];
  const float* b0      = (const float*)d_in[4];
  const float* W1      = (const float*)d_in[5];
  const float* b1      = (const float*)d_in[6];
  const float* Wsm     = (const float*)d_in[7];
  const float* sb      = (const float*)d_in[8];

  char* ws = (char*)d_ws;
  size_t off = 0;
  auto alloc = [&](size_t bytes)->char*{
    char* p = ws + off; off += (bytes + 255) & ~(size_t)255; return p;
  };
  unsigned short* Xbf  = (unsigned short*)alloc(8192ull*256*2);
  unsigned short* W0xT = (unsigned short*)alloc(1024ull*256*2);
  unsigned short* W0hT = (unsigned short*)alloc(1024ull*256*2);
  unsigned short* W1T  = (unsigned short*)alloc(1024ull*512*2);
  unsigned short* WsT  = (unsigned short*)alloc(16000ull*256*2);
  float*          Z0x  = (float*)         alloc(8192ull*1024*4);
  u64*            h0h  = (u64*)           alloc(128ull*2048*8);   // h0 history [t][kb][b][8]
  u64*            h1h  = (u64*)           alloc(128ull*2048*8);
  unsigned short* H1bf = (unsigned short*)alloc(8192ull*256*2);
  float*          S    = (float*)         alloc(8192ull*4);
  float*          LT   = (float*)         alloc(8192ull*4);
  unsigned*       flag0= (unsigned*)      alloc(128*4);
  unsigned*       flag1= (unsigned*)      alloc(128*4);

  hipMemsetAsync(S,     0, 8192ull*4, stream);
  hipMemsetAsync(flag0, 0, 2*((128*4 + 255) & ~255), stream);  // flag0+flag1 contiguous
  hipMemsetAsync(d_out, 0, 4, stream);

  k_gather<<<dim3(8192), dim3(256), 0, stream>>>(input, emb, Xbf);
  k_transpose<1,1><<<dim3(32, 8),  dim3(32,8), 0, stream>>>(W0,  (void*)W0xT, 256, 1024, 1024, 0);
  k_transpose<1,1><<<dim3(32, 8),  dim3(32,8), 0, stream>>>(W0,  (void*)W0hT, 256, 1024, 1024, 256);
  k_transpose<1,1><<<dim3(32, 16), dim3(32,8), 0, stream>>>(W1,  (void*)W1T,  512, 1024, 1024, 0);
  k_transpose<1,0><<<dim3(500, 8), dim3(32,8), 0, stream>>>(Wsm, (void*)WsT,  256, 16000, 16000, 0);

  // Z0x = X @ W0[:256,:] + b0   (M=8192 r'=(t,b), N=1024 n', K=256); m-major blocks
  k_gemm<0><<<dim3(64, 8), dim3(256), 0, stream>>>(Xbf, W0xT, Z0x, b0, nullptr, nullptr, nullptr);

  // persistent LSTM (24 WGs cooperative; flag-notify dataflow)
  void* kargs[] = { (void*)&Z0x, (void*)&W0hT, (void*)&W1T, (void*)&b1,
                    (void*)&h0h, (void*)&h1h, (void*)&H1bf, (void*)&flag0, (void*)&flag1 };
  hipLaunchCooperativeKernel((void*)k_lstm, dim3(24), dim3(256), kargs, 0, stream);

  // fused projection + log-softmax partials (M=8192 r=(b,t), N=16000, K=256);
  // dual-m tiles: 256 m-rows per block, m-major fast for B-panel L2 reuse
  k_gemm2<<<dim3(32, 125), dim3(256), 0, stream>>>(H1bf, WsT, sb, targets, S, LT);

  k_reduce<<<dim3(32), dim3(256), 0, stream>>>(S, LT, (float*)d_out);
}

// Round 8
// 844.475 us; speedup vs baseline: 1.0628x; 1.0519x over previous
//
#include <hip/hip_runtime.h>
#include <hip/hip_bf16.h>
#include <stdint.h>

typedef __attribute__((ext_vector_type(8))) short short8;
typedef __attribute__((ext_vector_type(4))) float f32x4;
typedef unsigned long long u64;

#define DI static __device__ __forceinline__

DI unsigned short f2b(float f){
  unsigned u = __float_as_uint(f);
  u = (u + 0x7FFFu + ((u >> 16) & 1u)) >> 16;
  return (unsigned short)u;
}
DI float sigm(float x){ return 1.0f / (1.0f + __expf(-x)); }
DI float tanh_(float x){ return 1.0f - 2.0f / (__expf(2.0f*x) + 1.0f); } // safe at +/-inf
DI unsigned pk2(unsigned short a, unsigned short b){ return (unsigned)a | ((unsigned)b << 16); }

// counted vmcnt wait for phase ks of an 8-load chunk sequence (immediate operand)
#define WAIT_PHASE(ks)                                                        \
  switch (ks){                                                                \
    case 0: asm volatile("s_waitcnt vmcnt(7)" ::: "memory"); break;           \
    case 1: asm volatile("s_waitcnt vmcnt(6)" ::: "memory"); break;           \
    case 2: asm volatile("s_waitcnt vmcnt(5)" ::: "memory"); break;           \
    case 3: asm volatile("s_waitcnt vmcnt(4)" ::: "memory"); break;           \
    case 4: asm volatile("s_waitcnt vmcnt(3)" ::: "memory"); break;           \
    case 5: asm volatile("s_waitcnt vmcnt(2)" ::: "memory"); break;           \
    case 6: asm volatile("s_waitcnt vmcnt(1)" ::: "memory"); break;           \
    default: asm volatile("s_waitcnt vmcnt(0)" ::: "memory"); break;          \
  }

// ---- embedding gather: Xbf[r' = t*64+b][256] = bf16(emb[input[b][t]])
__global__ void k_gather(const int* __restrict__ inp, const float* __restrict__ emb,
                         unsigned short* __restrict__ Xbf){
  int r = blockIdx.x;            // r' = t*64 + b
  int t = r >> 6, b = r & 63;
  int idx = inp[b*128 + t];
  float v = emb[(size_t)idx*256 + threadIdx.x];
  Xbf[(size_t)r*256 + threadIdx.x] = f2b(v);
}

// ---- transpose src[R][C] (rows row0..row0+R-1, ld) -> dst[n(C)][R]
// BF: bf16 output. REORD: gate-interleave columns n' = (c&255)*4 + (c>>8)
template<int BF, int REORD>
__global__ void k_transpose(const float* __restrict__ src, void* __restrict__ dst,
                            int R, int C, int ld, int row0){
  __shared__ float tile[32][33];
  int tx = threadIdx.x, ty = threadIdx.y;
  int x = blockIdx.x*32 + tx;
  for (int i = 0; i < 4; i++){
    int y = blockIdx.y*32 + ty + i*8;
    if (x < C && y < R) tile[ty + i*8][tx] = src[(size_t)(row0 + y)*ld + x];
  }
  __syncthreads();
  int y2 = blockIdx.y*32 + tx;                 // R index
  for (int i = 0; i < 4; i++){
    int x2 = blockIdx.x*32 + ty + i*8;         // C index
    if (x2 < C && y2 < R){
      float v = tile[tx][ty + i*8];
      int n = REORD ? ((x2 & 255)*4 + (x2 >> 8)) : x2;
      if (BF) ((unsigned short*)dst)[(size_t)n*R + y2] = f2b(v);
      else    ((float*)dst)[(size_t)n*R + y2] = v;
    }
  }
}

// ---- MFMA GEMM (verified m97 single-buffer pattern): C[m][n] = sum_k A[m][k]*Bt[n][k]
// Block mapping: m0 = blockIdx.x (fast) so consecutive blocks share the same B-tile (L2 reuse).
// EPI 0: Z0x store (+bias b0 with gate-reorder un-map), rows r'=(t,b) -> Z0x[t][n'][b]
// EPI 1: fused softmax partial: S[row] += sum exp(logit+bias); LT[row] = logit_tgt
template<int EPI>
__launch_bounds__(256, 2)
__global__ void k_gemm(const unsigned short* __restrict__ A, const unsigned short* __restrict__ Bt,
                       float* __restrict__ outZ, const float* __restrict__ bias,
                       const int* __restrict__ tgt, float* __restrict__ S, float* __restrict__ LT){
  __shared__ unsigned short As[128*64];
  __shared__ unsigned short Bs[128*64];
  __shared__ int tgt_s[128];
  const int m0 = blockIdx.x*128, n0 = blockIdx.y*128;
  const int tid = threadIdx.x;
  const int w = tid >> 6, l = tid & 63;
  const int quad = l >> 4, l15 = l & 15;
  const int wm = (w >> 1)*64, wn = (w & 1)*64;
  const int lrow = l >> 3, ls = l & 7;         // lane -> (row-in-group, slot)
  f32x4 acc[4][4] = {};
  if (EPI == 1 && tid < 128) tgt_s[tid] = tgt[m0 + tid];

  for (int k0 = 0; k0 < 256; k0 += 64){
    #pragma unroll
    for (int it = 0; it < 4; it++){
      int row = it*32 + w*8 + lrow;
      int csrc = ls ^ (row & 7);               // XOR swizzle: slot s holds chunk s^(row&7)
      __builtin_amdgcn_global_load_lds(
        (const __attribute__((address_space(1))) unsigned*)&A[(size_t)(m0+row)*256 + k0 + csrc*8],
        (__attribute__((address_space(3))) unsigned*)&As[(it*32 + w*8)*64], 16, 0, 0);
      __builtin_amdgcn_global_load_lds(
        (const __attribute__((address_space(1))) unsigned*)&Bt[(size_t)(n0+row)*256 + k0 + csrc*8],
        (__attribute__((address_space(3))) unsigned*)&Bs[(it*32 + w*8)*64], 16, 0, 0);
    }
    __syncthreads();
    #pragma unroll
    for (int ks = 0; ks < 64; ks += 32){
      const int cki = (ks >> 3) + quad;        // k-chunk index 0..7
      short8 af[4], bfr[4];
      #pragma unroll
      for (int i = 0; i < 4; i++){
        int row = wm + i*16 + l15;
        af[i]  = *(short8*)&As[row*64 + (cki ^ (row & 7))*8];
      }
      #pragma unroll
      for (int j = 0; j < 4; j++){
        int row = wn + j*16 + l15;
        bfr[j] = *(short8*)&Bs[row*64 + (cki ^ (row & 7))*8];
      }
      #pragma unroll
      for (int i = 0; i < 4; i++)
        #pragma unroll
        for (int j = 0; j < 4; j++)
          acc[i][j] = __builtin_amdgcn_mfma_f32_16x16x32_bf16(af[i], bfr[j], acc[i][j], 0, 0, 0);
    }
    __syncthreads();
  }

  if (EPI == 0){
    #pragma unroll
    for (int i = 0; i < 4; i++){
      int mg = m0 + wm + i*16 + quad*4;        // rows mg..mg+3 in this reg quad
      int t = mg >> 6, b = mg & 63;
      #pragma unroll
      for (int j = 0; j < 4; j++){
        int ng = n0 + wn + j*16 + l15;         // n' (gate-interleaved)
        float bb = bias[(ng & 3)*256 + (ng >> 2)];
        f32x4 v = acc[i][j];
        v[0] += bb; v[1] += bb; v[2] += bb; v[3] += bb;
        *(f32x4*)&outZ[((size_t)t*1024 + ng)*64 + b] = v;
      }
    }
  } else {
    #pragma unroll
    for (int i = 0; i < 4; i++){
      float rs[4] = {0.f,0.f,0.f,0.f};
      #pragma unroll
      for (int j = 0; j < 4; j++){
        int ng = n0 + wn + j*16 + l15;
        float bb = bias[ng];
        f32x4 v = acc[i][j];
        #pragma unroll
        for (int r = 0; r < 4; r++){
          float e = v[r] + bb;
          int mloc = wm + i*16 + quad*4 + r;
          if (tgt_s[mloc] == ng) LT[m0 + mloc] = e;
          rs[r] += __expf(e);
        }
      }
      #pragma unroll
      for (int r = 0; r < 4; r++){
        float s = rs[r];
        s += __shfl_xor(s, 1, 16);
        s += __shfl_xor(s, 2, 16);
        s += __shfl_xor(s, 4, 16);
        s += __shfl_xor(s, 8, 16);
        if (l15 == 0) atomicAdd(&S[m0 + wm + i*16 + quad*4 + r], s);
      }
    }
  }
}

// ---- persistent 2-layer LSTM, 24 WGs cooperative, flag-notify dataflow.
// WG 0..7: layer0 (32 units each); WG 8..23: layer1 (16 units each). Weights in regs.
// Protocol per step t (UNCHANGED, verified): producers store h (agent scope),
// s_waitcnt(0), __syncthreads, tid0 atomicAdd(flag[t]). Consumers: tid0 spins on
// flag[t] until quorum, then bulk global_load_lds stage.
// NEW (this round): the critical-path h0 stage+consume is chunk-pipelined —
// stage region it feeds exactly MFMA phase ks==it, so per-phase counted
// vmcnt(7-ks) + raw s_barrier lets the 32KB transfer stream under the MFMAs
// of earlier chunks instead of a full vmcnt(0) drain before any compute.
__launch_bounds__(256, 1)
__global__ void k_lstm(const float* __restrict__ Z0x,          // [128 t][1024 n'][64 b] f32 (b0 folded)
                       const unsigned short* __restrict__ W0h, // [1024 n'][256 k] bf16
                       const unsigned short* __restrict__ W1,  // [1024 n'][512 k] bf16
                       const float* __restrict__ b1,
                       u64* __restrict__ h0h,                  // [128 t][2048] = [kb][b][8] bf16
                       u64* __restrict__ h1h,                  // [128 t][2048]
                       unsigned short* __restrict__ H1bf,      // [b*128+t][256 u]
                       unsigned* __restrict__ flag0,           // [128]
                       unsigned* __restrict__ flag1){          // [128]
  __shared__ __align__(16) char smraw[65536];        // union: h-frag stage | z scratch
  unsigned short* hs = (unsigned short*)smraw;
  float* zl = (float*)smraw;

  const int wg = blockIdx.x;
  const bool L0 = (wg < 8);
  const int tid = threadIdx.x;
  const int w = tid >> 6, l = tid & 63, quad = l >> 4, l15 = l & 15;
  const int b = tid & 63;
  const unsigned short* h0s = (const unsigned short*)h0h;
  const unsigned short* h1s = (const unsigned short*)h1h;

  short8 bw[16];               // persistent weight fragments (64 VGPRs)
  float c_st[8];
  float b1r[16];
  #pragma unroll
  for (int i = 0; i < 8; i++) c_st[i] = 0.f;

  if (L0){
    const int n0 = wg*128;
    #pragma unroll
    for (int j = 0; j < 2; j++)
      #pragma unroll
      for (int ks = 0; ks < 8; ks++)
        bw[j*8+ks] = *(const short8*)&W0h[(size_t)(n0 + w*32 + j*16 + l15)*256 + ks*32 + quad*8];
  } else {
    const int n0 = (wg-8)*64;
    #pragma unroll
    for (int ks = 0; ks < 16; ks++)
      bw[ks] = *(const short8*)&W1[(size_t)(n0 + w*16 + l15)*512 + ks*32 + quad*8];
    const int u0 = (wg-8)*16, ul0 = w*4;
    #pragma unroll
    for (int ul = 0; ul < 4; ul++)
      #pragma unroll
      for (int g = 0; g < 4; g++)
        b1r[ul*4+g] = b1[g*256 + u0 + ul0 + ul];
  }

  if (L0){
    const int n0 = wg*128;
    for (int t = 0; t < 128; t++){
      f32x4 acc[4][2];
      #pragma unroll
      for (int i = 0; i < 4; i++)
        #pragma unroll
        for (int j = 0; j < 2; j++){
          int cl = w*32 + j*16 + l15;
          acc[i][j] = *(const f32x4*)&Z0x[((size_t)t*1024 + n0 + cl)*64 + i*16 + quad*4];
        }
      if (t > 0){
        if (tid == 0)
          while (__hip_atomic_load(flag0 + (t-1), __ATOMIC_RELAXED, __HIP_MEMORY_SCOPE_AGENT) < 8u)
            __builtin_amdgcn_s_sleep(1);
        __syncthreads();
        #pragma unroll
        for (int it = 0; it < 8; it++){
          int c = it*256 + w*64 + l;
          __builtin_amdgcn_global_load_lds(
            (const __attribute__((address_space(1))) unsigned*)&h0s[(size_t)(t-1)*16384 + (size_t)c*8],
            (__attribute__((address_space(3))) unsigned*)&hs[(it*256 + w*64)*8], 16, 0, 0);
        }
        // chunk-pipelined consume: phase ks reads rows ks*4+quad = stage region it==ks
        #pragma unroll
        for (int ks = 0; ks < 8; ks++){
          WAIT_PHASE(ks);                      // own it<=ks loads landed
          __builtin_amdgcn_s_barrier();        // all threads' it<=ks loads landed
          __builtin_amdgcn_sched_barrier(0);
          short8 a[4];
          #pragma unroll
          for (int i = 0; i < 4; i++)
            a[i] = *(const short8*)&hs[(((ks*4+quad)*64) + i*16 + l15)*8];
          #pragma unroll
          for (int i = 0; i < 4; i++)
            #pragma unroll
            for (int j = 0; j < 2; j++)
              acc[i][j] = __builtin_amdgcn_mfma_f32_16x16x32_bf16(a[i], bw[j*8+ks], acc[i][j], 0, 0, 0);
        }
        __syncthreads();                       // hs reads done; zl aliases hs
      }
      #pragma unroll
      for (int i = 0; i < 4; i++)
        #pragma unroll
        for (int j = 0; j < 2; j++){
          int cl = w*32 + j*16 + l15;
          *(f32x4*)&zl[cl*68 + i*16 + quad*4] = acc[i][j];
        }
      __syncthreads();
      // cell update: 8 units per thread
      const int ul0 = w*8;
      unsigned short hout[8];
      #pragma unroll
      for (int ui = 0; ui < 8; ui++){
        int cc = (ul0 + ui)*4;
        float zi = zl[(cc+0)*68 + b], zj = zl[(cc+1)*68 + b];
        float zf = zl[(cc+2)*68 + b], zo = zl[(cc+3)*68 + b];
        float c = c_st[ui]*sigm(zf + 1.0f) + sigm(zi)*tanh_(zj);
        c_st[ui] = c;
        hout[ui] = f2b(tanh_(c)*sigm(zo));
      }
      // publish (agent scope -> LLC write-through), then notify
      {
        u64 v0 = (u64)pk2(hout[0],hout[1]) | ((u64)pk2(hout[2],hout[3]) << 32);
        u64 v1 = (u64)pk2(hout[4],hout[5]) | ((u64)pk2(hout[6],hout[7]) << 32);
        size_t pbase = (size_t)t*2048 + ((size_t)(wg*4 + w)*64 + b)*2;
        __hip_atomic_store(h0h + pbase,     v0, __ATOMIC_RELAXED, __HIP_MEMORY_SCOPE_AGENT);
        __hip_atomic_store(h0h + pbase + 1, v1, __ATOMIC_RELAXED, __HIP_MEMORY_SCOPE_AGENT);
      }
      __builtin_amdgcn_s_waitcnt(0);           // stores LLC-acked
      __syncthreads();                         // all threads' stores acked; zl reads done
      if (tid == 0)
        __hip_atomic_fetch_add(flag0 + t, 1u, __ATOMIC_RELAXED, __HIP_MEMORY_SCOPE_AGENT);
    }
  } else {
    const int u0 = (wg-8)*16, ul0 = w*4;
    for (int t = 0; t < 128; t++){
      f32x4 acc[4];
      #pragma unroll
      for (int i = 0; i < 4; i++) acc[i] = (f32x4){0.f,0.f,0.f,0.f};
      if (t > 0){
        // h1(t-1): ready (we produced it); stage + MFMA its half while layer0 works on h0(t)
        if (tid == 0)
          while (__hip_atomic_load(flag1 + (t-1), __ATOMIC_RELAXED, __HIP_MEMORY_SCOPE_AGENT) < 16u)
            __builtin_amdgcn_s_sleep(1);
        __syncthreads();
        #pragma unroll
        for (int it = 0; it < 8; it++){
          int c = it*256 + w*64 + l;
          __builtin_amdgcn_global_load_lds(
            (const __attribute__((address_space(1))) unsigned*)&h1s[(size_t)(t-1)*16384 + (size_t)c*8],
            (__attribute__((address_space(3))) unsigned*)&hs[16384 + (it*256 + w*64)*8], 16, 0, 0);
        }
        __builtin_amdgcn_s_waitcnt(0);
        __syncthreads();
        #pragma unroll
        for (int ks = 8; ks < 16; ks++){       // kb 32..63 -> hs shorts 16384..32767
          short8 a[4];
          #pragma unroll
          for (int i = 0; i < 4; i++)
            a[i] = *(const short8*)&hs[(((ks*4+quad)*64) + i*16 + l15)*8];
          #pragma unroll
          for (int i = 0; i < 4; i++)
            acc[i] = __builtin_amdgcn_mfma_f32_16x16x32_bf16(a[i], bw[ks], acc[i], 0, 0, 0);
        }
      }
      // critical h0(t): chunk-pipelined stage+consume
      if (tid == 0)
        while (__hip_atomic_load(flag0 + t, __ATOMIC_RELAXED, __HIP_MEMORY_SCOPE_AGENT) < 8u)
          __builtin_amdgcn_s_sleep(1);
      __syncthreads();
      #pragma unroll
      for (int it = 0; it < 8; it++){
        int c = it*256 + w*64 + l;
        __builtin_amdgcn_global_load_lds(
          (const __attribute__((address_space(1))) unsigned*)&h0s[(size_t)t*16384 + (size_t)c*8],
          (__attribute__((address_space(3))) unsigned*)&hs[(it*256 + w*64)*8], 16, 0, 0);
      }
      #pragma unroll
      for (int ks = 0; ks < 8; ks++){
        WAIT_PHASE(ks);
        __builtin_amdgcn_s_barrier();
        __builtin_amdgcn_sched_barrier(0);
        short8 a[4];
        #pragma unroll
        for (int i = 0; i < 4; i++)
          a[i] = *(const short8*)&hs[(((ks*4+quad)*64) + i*16 + l15)*8];
        #pragma unroll
        for (int i = 0; i < 4; i++)
          acc[i] = __builtin_amdgcn_mfma_f32_16x16x32_bf16(a[i], bw[ks], acc[i], 0, 0, 0);
      }
      __syncthreads();                         // hs reads done; zl aliases hs
      {
        int cl = w*16 + l15;
        #pragma unroll
        for (int i = 0; i < 4; i++)
          *(f32x4*)&zl[cl*68 + i*16 + quad*4] = acc[i];
      }
      __syncthreads();
      // cell update: 4 units per thread
      unsigned short hout[4];
      #pragma unroll
      for (int ui = 0; ui < 4; ui++){
        int cc = (ul0 + ui)*4;
        float zi = zl[(cc+0)*68 + b] + b1r[ui*4+0];
        float zj = zl[(cc+1)*68 + b] + b1r[ui*4+1];
        float zf = zl[(cc+2)*68 + b] + b1r[ui*4+2];
        float zo = zl[(cc+3)*68 + b] + b1r[ui*4+3];
        float c = c_st[ui]*sigm(zf + 1.0f) + sigm(zi)*tanh_(zj);
        c_st[ui] = c;
        hout[ui] = f2b(tanh_(c)*sigm(zo));
      }
      {
        const int u = u0 + ul0;                // multiple of 4
        u64 v = (u64)pk2(hout[0],hout[1]) | ((u64)pk2(hout[2],hout[3]) << 32);
        size_t pbase = (size_t)t*2048 + ((size_t)(u >> 3)*64 + b)*2 + ((u & 4) >> 2);
        __hip_atomic_store(h1h + pbase, v, __ATOMIC_RELAXED, __HIP_MEMORY_SCOPE_AGENT);
        *(uint2*)&H1bf[((size_t)b*128 + t)*256 + u] = *(const uint2*)hout;   // plain store
      }
      __builtin_amdgcn_s_waitcnt(0);
      __syncthreads();
      if (tid == 0)
        __hip_atomic_fetch_add(flag1 + t, 1u, __ATOMIC_RELAXED, __HIP_MEMORY_SCOPE_AGENT);
    }
  }
}

// ---- final reduce: cost = mean(log(S) - LT), 32 blocks + one atomic each
__global__ void k_reduce(const float* __restrict__ S, const float* __restrict__ LT,
                         float* __restrict__ out){
  __shared__ float red[256];
  int r = blockIdx.x*256 + threadIdx.x;
  red[threadIdx.x] = __logf(S[r]) - LT[r];
  __syncthreads();
  for (int st = 128; st > 0; st >>= 1){
    if (threadIdx.x < st) red[threadIdx.x] += red[threadIdx.x + st];
    __syncthreads();
  }
  if (threadIdx.x == 0) atomicAdd(out, red[0] / 8192.0f);
}

extern "C" void kernel_launch(void* const* d_in, const int* in_sizes, int n_in,
                              void* d_out, int out_size, void* d_ws, size_t ws_size,
                              hipStream_t stream){
  const int*   input   = (const int*)  d_in[0];
  const int*   targets = (const int*)  d_in[1];
  const float* emb     = (const float*)d_in[2];
  const float* W0      = (const float*)d_in[3];
  const float* b0      = (const float*)d_in[4];
  const float* W1      = (const float*)d_in[5];
  const float* b1      = (const float*)d_in[6];
  const float* Wsm     = (const float*)d_in[7];
  const float* sb      = (const float*)d_in[8];

  char* ws = (char*)d_ws;
  size_t off = 0;
  auto alloc = [&](size_t bytes)->char*{
    char* p = ws + off; off += (bytes + 255) & ~(size_t)255; return p;
  };
  unsigned short* Xbf  = (unsigned short*)alloc(8192ull*256*2);
  unsigned short* W0xT = (unsigned short*)alloc(1024ull*256*2);
  unsigned short* W0hT = (unsigned short*)alloc(1024ull*256*2);
  unsigned short* W1T  = (unsigned short*)alloc(1024ull*512*2);
  unsigned short* WsT  = (unsigned short*)alloc(16000ull*256*2);
  float*          Z0x  = (float*)         alloc(8192ull*1024*4);
  u64*            h0h  = (u64*)           alloc(128ull*2048*8);   // h0 history [t][kb][b][8]
  u64*            h1h  = (u64*)           alloc(128ull*2048*8);
  unsigned short* H1bf = (unsigned short*)alloc(8192ull*256*2);
  float*          S    = (float*)         alloc(8192ull*4);
  float*          LT   = (float*)         alloc(8192ull*4);
  unsigned*       flag0= (unsigned*)      alloc(128*4);
  unsigned*       flag1= (unsigned*)      alloc(128*4);

  hipMemsetAsync(S,     0, 8192ull*4, stream);
  hipMemsetAsync(flag0, 0, 2*((128*4 + 255) & ~255), stream);  // flag0+flag1 contiguous
  hipMemsetAsync(d_out, 0, 4, stream);

  k_gather<<<dim3(8192), dim3(256), 0, stream>>>(input, emb, Xbf);
  k_transpose<1,1><<<dim3(32, 8),  dim3(32,8), 0, stream>>>(W0,  (void*)W0xT, 256, 1024, 1024, 0);
  k_transpose<1,1><<<dim3(32, 8),  dim3(32,8), 0, stream>>>(W0,  (void*)W0hT, 256, 1024, 1024, 256);
  k_transpose<1,1><<<dim3(32, 16), dim3(32,8), 0, stream>>>(W1,  (void*)W1T,  512, 1024, 1024, 0);
  k_transpose<1,0><<<dim3(500, 8), dim3(32,8), 0, stream>>>(Wsm, (void*)WsT,  256, 16000, 16000, 0);

  // Z0x = X @ W0[:256,:] + b0   (M=8192 r'=(t,b), N=1024 n', K=256); m-major blocks
  k_gemm<0><<<dim3(64, 8), dim3(256), 0, stream>>>(Xbf, W0xT, Z0x, b0, nullptr, nullptr, nullptr);

  // persistent LSTM (24 WGs cooperative; flag-notify dataflow)
  void* kargs[] = { (void*)&Z0x, (void*)&W0hT, (void*)&W1T, (void*)&b1,
                    (void*)&h0h, (void*)&h1h, (void*)&H1bf, (void*)&flag0, (void*)&flag1 };
  hipLaunchCooperativeKernel((void*)k_lstm, dim3(24), dim3(256), kargs, 0, stream);

  // fused projection + log-softmax partials (M=8192 r=(b,t), N=16000, K=256); m-major blocks
  k_gemm<1><<<dim3(64, 125), dim3(256), 0, stream>>>(H1bf, WsT, nullptr, sb, targets, S, LT);

  k_reduce<<<dim3(32), dim3(256), 0, stream>>>(S, LT, (float*)d_out);
}